// Round 15
// baseline (858.851 us; speedup 1.0000x reference)
//
#include <hip/hip_runtime.h>
#include <math.h>

// EGNN forward. P/Q factorization + CSR sort + fused MFMA edge kernel.
// Round 15: wave-specialized edge epilogue — waves 0-1 run the stage-4 agg
// scan concurrently with waves 2-3 running stage-3 (coord MFMA). No numeric
// changes vs round 14.

typedef __attribute__((ext_vector_type(8))) short bshort8;
typedef __attribute__((ext_vector_type(4))) float f32x4;
typedef unsigned short ushort;
typedef unsigned int uint;

__device__ __forceinline__ float silu_f(float x)
{
  return x * __builtin_amdgcn_rcpf(1.0f + __expf(-x));
}

__device__ __forceinline__ void bf16_split(float x, ushort& h, ushort& l)
{
  uint bx = __float_as_uint(x);
  ushort hb = (ushort)(bx >> 16);
  float hf = __uint_as_float((uint)hb << 16);
  float r = x - hf;
  l = (ushort)(__float_as_uint(r) >> 16);
  h = hb;
}

#define ROW_FMA(acc, scal, rowptr)                                                   \
  {                                                                                  \
    const float4* _w = (const float4*)(rowptr);                                      \
    _Pragma("unroll") for (int _j = 0; _j < 16; _j++)                                \
    {                                                                                \
      float4 _wv = _w[_j];                                                           \
      acc[4 * _j + 0] += (scal) * _wv.x;                                             \
      acc[4 * _j + 1] += (scal) * _wv.y;                                             \
      acc[4 * _j + 2] += (scal) * _wv.z;                                             \
      acc[4 * _j + 3] += (scal) * _wv.w;                                             \
    }                                                                                \
  }

// ---------------- proj ----------------
__global__ __launch_bounds__(256) void proj_kernel(
    const float* __restrict__ x, const float* __restrict__ W, const float* __restrict__ b,
    float* __restrict__ h, int N)
{
  __shared__ float sW[26 * 64];
  __shared__ float sb[64];
  for (int i = threadIdx.x; i < 26 * 64; i += 256) sW[i] = W[i];
  if (threadIdx.x < 64) sb[threadIdx.x] = b[threadIdx.x];
  __syncthreads();
  int n = blockIdx.x * 256 + threadIdx.x;
  if (n >= N) return;
  float acc[64];
#pragma unroll
  for (int j = 0; j < 64; j++) acc[j] = sb[j];
#pragma unroll
  for (int k = 0; k < 26; k++) {
    float xk = x[(size_t)n * 26 + k];
    ROW_FMA(acc, xk, sW + k * 64);
  }
  float4* h4 = (float4*)(h + (size_t)n * 64);
#pragma unroll
  for (int j4 = 0; j4 < 16; j4++) {
    float4 v;
    v.x = acc[4 * j4 + 0]; v.y = acc[4 * j4 + 1]; v.z = acc[4 * j4 + 2]; v.w = acc[4 * j4 + 3];
    h4[j4] = v;
  }
}

// ---------------- shared helpers for MFMA tile kernels ----------------
#define EB 128

__device__ __forceinline__ bshort8 lds_frag(const ushort* base, int edge, int kb)
{
  int byte = edge * 128 + kb * 2;
  byte ^= (edge & 7) << 4;
  return *(const bshort8*)((const char*)base + byte);
}

// stage a [128][64] fp32 tile -> bf16 hi/lo XOR-swizzled LDS (conflict-free b128)
__device__ __forceinline__ void stage_tile_f32(
    const float* __restrict__ src, int n0, int N, ushort* sHi, ushort* sLo, int t)
{
#pragma unroll
  for (int p = 0; p < 4; p++) {
    int nl = p * 32 + (t >> 3);
    int ks = t & 7;
    int n = n0 + nl;
    int base = nl * 128 + ks * 16;
    int swz = (nl & 7) << 4;
    if (n < N) {
      const float4* sp = (const float4*)(src + (size_t)n * 64) + ks * 2;
      float4 a0 = sp[0], a1 = sp[1];
      float va[8] = {a0.x, a0.y, a0.z, a0.w, a1.x, a1.y, a1.z, a1.w};
      ushort hh[8], ll[8];
#pragma unroll
      for (int kk = 0; kk < 8; kk++) bf16_split(va[kk], hh[kk], ll[kk]);
      uint4 hv, lv;
      hv.x = (uint)hh[0] | ((uint)hh[1] << 16);
      hv.y = (uint)hh[2] | ((uint)hh[3] << 16);
      hv.z = (uint)hh[4] | ((uint)hh[5] << 16);
      hv.w = (uint)hh[6] | ((uint)hh[7] << 16);
      lv.x = (uint)ll[0] | ((uint)ll[1] << 16);
      lv.y = (uint)ll[2] | ((uint)ll[3] << 16);
      lv.z = (uint)ll[4] | ((uint)ll[5] << 16);
      lv.w = (uint)ll[6] | ((uint)ll[7] << 16);
      *(uint4*)((char*)sHi + (base ^ swz)) = hv;
      *(uint4*)((char*)sLo + (base ^ swz)) = lv;
    } else {
      uint4 z; z.x = 0; z.y = 0; z.z = 0; z.w = 0;
      *(uint4*)((char*)sHi + (base ^ swz)) = z;
      *(uint4*)((char*)sLo + (base ^ swz)) = z;
    }
  }
}

// 3-split GEMM panel: acc[et] += Wt(col) · A(node) over one 64-k panel.
#define PANEL_MFMA(accv, bhp, blp, sHi, sLo)                                         \
  {                                                                                  \
    bshort8 wh0 = *(const bshort8*)(bhp);                                            \
    bshort8 wh1 = *(const bshort8*)((bhp) + 32);                                     \
    bshort8 wl0 = *(const bshort8*)(blp);                                            \
    bshort8 wl1 = *(const bshort8*)((blp) + 32);                                     \
    _Pragma("unroll") for (int et = 0; et < 8; et++)                                 \
    {                                                                                \
      int nd = et * 16 + lane16;                                                     \
      bshort8 ah0 = lds_frag(sHi, nd, kq * 8);                                       \
      bshort8 ah1 = lds_frag(sHi, nd, 32 + kq * 8);                                  \
      bshort8 al0 = lds_frag(sLo, nd, kq * 8);                                       \
      bshort8 al1 = lds_frag(sLo, nd, 32 + kq * 8);                                  \
      f32x4 a = accv[et];                                                            \
      a = __builtin_amdgcn_mfma_f32_16x16x32_bf16(wh0, ah0, a, 0, 0, 0);             \
      a = __builtin_amdgcn_mfma_f32_16x16x32_bf16(wh1, ah1, a, 0, 0, 0);             \
      a = __builtin_amdgcn_mfma_f32_16x16x32_bf16(wh0, al0, a, 0, 0, 0);             \
      a = __builtin_amdgcn_mfma_f32_16x16x32_bf16(wh1, al1, a, 0, 0, 0);             \
      a = __builtin_amdgcn_mfma_f32_16x16x32_bf16(wl0, ah0, a, 0, 0, 0);             \
      a = __builtin_amdgcn_mfma_f32_16x16x32_bf16(wl1, ah1, a, 0, 0, 0);             \
      accv[et] = a;                                                                  \
    }                                                                                \
  }

// ---------------- MFMA premul (layer 0) ----------------
__global__ __launch_bounds__(256) void premul_mfma_kernel(
    const float* __restrict__ h, const ushort* __restrict__ pqh, const ushort* __restrict__ pql,
    float* __restrict__ P, float* __restrict__ Q, int N)
{
  __shared__ ushort sAhi[EB * 64];
  __shared__ ushort sAlo[EB * 64];
  int t = threadIdx.x;
  int n0 = blockIdx.x * EB;
  stage_tile_f32(h, n0, N, sAhi, sAlo, t);
  __syncthreads();

  int l = t & 63, wv = t >> 6, lane16 = l & 15, kq = l >> 4;
  int col = wv * 16 + kq * 4;

  f32x4 acc[8];
#pragma unroll
  for (int et = 0; et < 8; et++) { f32x4 z = {0.f, 0.f, 0.f, 0.f}; acc[et] = z; }
  {
    const ushort* bh = pqh + (wv * 16 + lane16) * 64 + kq * 8;
    const ushort* bl = pql + (wv * 16 + lane16) * 64 + kq * 8;
    PANEL_MFMA(acc, bh, bl, sAhi, sAlo);
  }
#pragma unroll
  for (int et = 0; et < 8; et++) {
    int n = n0 + et * 16 + lane16;
    if (n < N) {
      float4 v; v.x = acc[et][0]; v.y = acc[et][1]; v.z = acc[et][2]; v.w = acc[et][3];
      *(float4*)(P + (size_t)n * 64 + col) = v;
    }
  }
#pragma unroll
  for (int et = 0; et < 8; et++) { f32x4 z = {0.f, 0.f, 0.f, 0.f}; acc[et] = z; }
  {
    const ushort* bh = pqh + 4096 + (wv * 16 + lane16) * 64 + kq * 8;
    const ushort* bl = pql + 4096 + (wv * 16 + lane16) * 64 + kq * 8;
    PANEL_MFMA(acc, bh, bl, sAhi, sAlo);
  }
#pragma unroll
  for (int et = 0; et < 8; et++) {
    int n = n0 + et * 16 + lane16;
    if (n < N) {
      float4 v; v.x = acc[et][0]; v.y = acc[et][1]; v.z = acc[et][2]; v.w = acc[et][3];
      *(float4*)(Q + (size_t)n * 64 + col) = v;
    }
  }
}

// ---------------- MFMA node MLP (+fused premul for next layer) ----------------
template <int PREMUL>
__global__ __launch_bounds__(256) void node_mfma_kernel(
    float* __restrict__ h, const float* __restrict__ agg,
    const ushort* __restrict__ n1h, const ushort* __restrict__ n1l,
    const float* __restrict__ b1,
    const ushort* __restrict__ n2h, const ushort* __restrict__ n2l,
    const float* __restrict__ b2,
    const ushort* __restrict__ pqh, const ushort* __restrict__ pql,
    float* __restrict__ P, float* __restrict__ Q, int N)
{
  __shared__ ushort sAhi[EB * 64];
  __shared__ ushort sAlo[EB * 64];
  __shared__ float sb1v[64], sb2v[64];
  int t = threadIdx.x;
  int n0 = blockIdx.x * EB;
  if (t < 64) { sb1v[t] = b1[t]; sb2v[t] = b2[t]; }

  stage_tile_f32(h, n0, N, sAhi, sAlo, t);
  __syncthreads();

  int l = t & 63, wv = t >> 6, lane16 = l & 15, kq = l >> 4;
  int col = wv * 16 + kq * 4;

  f32x4 acc[8];
#pragma unroll
  for (int et = 0; et < 8; et++) { f32x4 z = {0.f, 0.f, 0.f, 0.f}; acc[et] = z; }
  {
    const ushort* bh = n1h + (wv * 16 + lane16) * 128 + kq * 8;
    const ushort* bl = n1l + (wv * 16 + lane16) * 128 + kq * 8;
    PANEL_MFMA(acc, bh, bl, sAhi, sAlo);
  }
  __syncthreads();
  stage_tile_f32(agg, n0, N, sAhi, sAlo, t);
  __syncthreads();
  {
    const ushort* bh = n1h + (wv * 16 + lane16) * 128 + 64 + kq * 8;
    const ushort* bl = n1l + (wv * 16 + lane16) * 128 + 64 + kq * 8;
    PANEL_MFMA(acc, bh, bl, sAhi, sAlo);
  }
  __syncthreads();

  {
    float b1r[4];
#pragma unroll
    for (int r = 0; r < 4; r++) b1r[r] = sb1v[col + r];
#pragma unroll
    for (int et = 0; et < 8; et++) {
      int nd = et * 16 + lane16;
      ushort uh[4], ul[4];
#pragma unroll
      for (int r = 0; r < 4; r++) {
        float uv = silu_f(acc[et][r] + b1r[r]);
        bf16_split(uv, uh[r], ul[r]);
      }
      int byte = (nd * 128 + col * 2) ^ ((nd & 7) << 4);
      uint2 hv, lv;
      hv.x = (uint)uh[0] | ((uint)uh[1] << 16);
      hv.y = (uint)uh[2] | ((uint)uh[3] << 16);
      lv.x = (uint)ul[0] | ((uint)ul[1] << 16);
      lv.y = (uint)ul[2] | ((uint)ul[3] << 16);
      *(uint2*)((char*)sAhi + byte) = hv;
      *(uint2*)((char*)sAlo + byte) = lv;
    }
  }
  __syncthreads();

#pragma unroll
  for (int et = 0; et < 8; et++) { f32x4 z = {0.f, 0.f, 0.f, 0.f}; acc[et] = z; }
  {
    const ushort* bh = n2h + (wv * 16 + lane16) * 64 + kq * 8;
    const ushort* bl = n2l + (wv * 16 + lane16) * 64 + kq * 8;
    PANEL_MFMA(acc, bh, bl, sAhi, sAlo);
  }
  uint2 hnh[8], hnl[8];
  {
    float b2r[4];
#pragma unroll
    for (int r = 0; r < 4; r++) b2r[r] = sb2v[col + r];
#pragma unroll
    for (int et = 0; et < 8; et++) {
      int n = n0 + et * 16 + lane16;
      float hn[4];
      if (n < N) {
        float4 hv = *(float4*)(h + (size_t)n * 64 + col);
        hn[0] = hv.x + acc[et][0] + b2r[0];
        hn[1] = hv.y + acc[et][1] + b2r[1];
        hn[2] = hv.z + acc[et][2] + b2r[2];
        hn[3] = hv.w + acc[et][3] + b2r[3];
        float4 sv; sv.x = hn[0]; sv.y = hn[1]; sv.z = hn[2]; sv.w = hn[3];
        *(float4*)(h + (size_t)n * 64 + col) = sv;
      } else {
        hn[0] = hn[1] = hn[2] = hn[3] = 0.f;
      }
      if (PREMUL) {
        ushort sh[4], sl[4];
#pragma unroll
        for (int r = 0; r < 4; r++) bf16_split(hn[r], sh[r], sl[r]);
        hnh[et].x = (uint)sh[0] | ((uint)sh[1] << 16);
        hnh[et].y = (uint)sh[2] | ((uint)sh[3] << 16);
        hnl[et].x = (uint)sl[0] | ((uint)sl[1] << 16);
        hnl[et].y = (uint)sl[2] | ((uint)sl[3] << 16);
      }
    }
  }

  if (PREMUL) {
    __syncthreads();
#pragma unroll
    for (int et = 0; et < 8; et++) {
      int nd = et * 16 + lane16;
      int byte = (nd * 128 + col * 2) ^ ((nd & 7) << 4);
      *(uint2*)((char*)sAhi + byte) = hnh[et];
      *(uint2*)((char*)sAlo + byte) = hnl[et];
    }
    __syncthreads();
#pragma unroll
    for (int et = 0; et < 8; et++) { f32x4 z = {0.f, 0.f, 0.f, 0.f}; acc[et] = z; }
    {
      const ushort* bh = pqh + (wv * 16 + lane16) * 64 + kq * 8;
      const ushort* bl = pql + (wv * 16 + lane16) * 64 + kq * 8;
      PANEL_MFMA(acc, bh, bl, sAhi, sAlo);
    }
#pragma unroll
    for (int et = 0; et < 8; et++) {
      int n = n0 + et * 16 + lane16;
      if (n < N) {
        float4 v; v.x = acc[et][0]; v.y = acc[et][1]; v.z = acc[et][2]; v.w = acc[et][3];
        *(float4*)(P + (size_t)n * 64 + col) = v;
      }
    }
#pragma unroll
    for (int et = 0; et < 8; et++) { f32x4 z = {0.f, 0.f, 0.f, 0.f}; acc[et] = z; }
    {
      const ushort* bh = pqh + 4096 + (wv * 16 + lane16) * 64 + kq * 8;
      const ushort* bl = pql + 4096 + (wv * 16 + lane16) * 64 + kq * 8;
      PANEL_MFMA(acc, bh, bl, sAhi, sAlo);
    }
#pragma unroll
    for (int et = 0; et < 8; et++) {
      int n = n0 + et * 16 + lane16;
      if (n < N) {
        float4 v; v.x = acc[et][0]; v.y = acc[et][1]; v.z = acc[et][2]; v.w = acc[et][3];
        *(float4*)(Q + (size_t)n * 64 + col) = v;
      }
    }
  }
}

// ---------------- CSR build ----------------
__global__ __launch_bounds__(256) void hist_kernel(
    const int* __restrict__ row, int* __restrict__ cnt, int E)
{
  int e = blockIdx.x * 256 + threadIdx.x;
  if (e < E) atomicAdd(&cnt[row[e]], 1);
}

__global__ __launch_bounds__(1024) void scan_kernel(
    const int* __restrict__ cnt, int* __restrict__ rowptr, int* __restrict__ cursor, int N, int E)
{
  __shared__ int part[1024];
  int t = threadIdx.x;
  int chunk = (N + 1023) >> 10;
  int lo = t * chunk;
  int hi = lo + chunk;
  if (lo > N) lo = N;
  if (hi > N) hi = N;
  int s = 0;
  for (int i = lo; i < hi; i++) s += cnt[i];
  part[t] = s;
  __syncthreads();
  for (int off = 1; off < 1024; off <<= 1) {
    int v = 0;
    if (t >= off) v = part[t - off];
    __syncthreads();
    if (t >= off) part[t] += v;
    __syncthreads();
  }
  int run = part[t] - s;
  for (int i = lo; i < hi; i++) {
    rowptr[i] = run;
    cursor[i] = run;
    run += cnt[i];
  }
  if (t == 0) rowptr[N] = E;
}

__global__ __launch_bounds__(256) void scatter_kernel(
    const int* __restrict__ row, const int* __restrict__ col, const float* __restrict__ eattr,
    int* __restrict__ cursor, int* __restrict__ srow, int* __restrict__ scol,
    float* __restrict__ sea4, int E)
{
  int e = blockIdx.x * 256 + threadIdx.x;
  if (e >= E) return;
  int r = row[e];
  int p = atomicAdd(&cursor[r], 1);
  srow[p] = r;
  scol[p] = col[e];
  float4 v;
  v.x = eattr[(size_t)e * 3 + 0];
  v.y = eattr[(size_t)e * 3 + 1];
  v.z = eattr[(size_t)e * 3 + 2];
  v.w = 0.f;
  ((float4*)sea4)[p] = v;
}

// ---------------- weight prep: bf16 hi/lo transposed tables ----------------
__global__ __launch_bounds__(256) void prep_wt_kernel(
    const float* __restrict__ W2all, const float* __restrict__ C1all,
    ushort* __restrict__ w2h, ushort* __restrict__ w2l,
    ushort* __restrict__ c1h, ushort* __restrict__ c1l)
{
  int idx = blockIdx.x * 256 + threadIdx.x;
  if (idx >= 4 * 4096) return;
  int layer = idx >> 12, rem = idx & 4095;
  int k = rem >> 6, c = rem & 63;
  int oidx = layer * 4096 + c * 64 + k;
  ushort h, l;
  bf16_split(W2all[idx], h, l);
  w2h[oidx] = h; w2l[oidx] = l;
  if (layer < 3) {
    bf16_split(C1all[idx], h, l);
    c1h[oidx] = h; c1l[oidx] = l;
  }
}

__global__ __launch_bounds__(256) void prep_nd_kernel(
    const float* __restrict__ ndW1, const float* __restrict__ ndW2,
    const float* __restrict__ msgW1,
    ushort* __restrict__ n1h, ushort* __restrict__ n1l,
    ushort* __restrict__ n2h, ushort* __restrict__ n2l,
    ushort* __restrict__ pqh, ushort* __restrict__ pql)
{
  int idx = blockIdx.x * 256 + threadIdx.x;
  if (idx < 4 * 8192) {
    int i = idx >> 13, rem = idx & 8191;
    int k = rem >> 6, c = rem & 63;
    ushort h, l;
    bf16_split(ndW1[idx], h, l);
    int o = i * 8192 + c * 128 + k;
    n1h[o] = h; n1l[o] = l;
  }
  if (idx < 4 * 4096) {
    int i = idx >> 12, rem = idx & 4095;
    int k = rem >> 6, c = rem & 63;
    ushort h, l;
    bf16_split(ndW2[idx], h, l);
    int o = i * 4096 + c * 64 + k;
    n2h[o] = h; n2l[o] = l;
  }
  if (idx < 4 * 8192) {
    int i = idx >> 13, rem = idx & 8191;
    int k = rem >> 6, c = rem & 63;
    ushort h, l;
    bf16_split(msgW1[(size_t)i * 132 * 64 + k * 64 + c], h, l);
    int o = i * 8192 + (k >> 6) * 4096 + c * 64 + (k & 63);
    pqh[o] = h; pql[o] = l;
  }
}

// ---------------- fused edge kernel (wave-specialized epilogue) ----------------
template <int COORD>
__global__ __launch_bounds__(256) void edge_fused_kernel(
    const int* __restrict__ srow, const int* __restrict__ scol, const int* __restrict__ rowptr,
    const float* __restrict__ posr, float* __restrict__ posw,
    const float* __restrict__ sea4,
    const float* __restrict__ P, const float* __restrict__ Q,
    const float* __restrict__ W1t, const float* __restrict__ b1,
    const ushort* __restrict__ w2h, const ushort* __restrict__ w2l,
    const float* __restrict__ b2,
    const ushort* __restrict__ c1h, const ushort* __restrict__ c1l,
    const float* __restrict__ cb1, const float* __restrict__ cW2,
    const float* __restrict__ cb2,
    float* __restrict__ agg, int E)
{
  __shared__ ushort sUhi[EB * 64];
  __shared__ ushort sUlo[EB * 64];
  __shared__ float sW1t[4 * 64];
  __shared__ float sb1v[64], sb2v[64];
  __shared__ float sDiff[3][EB];
  __shared__ float sWe[EB];
  __shared__ int sShare[COORD ? EB * 4 : EB];  // s_srow then sPart
  __shared__ float scb1v[COORD ? 64 : 1];
  __shared__ float scW2v[COORD ? 64 : 1];
  __shared__ int sSlotCnt[2];
  __shared__ int sSlotStart[EB + 2];
  __shared__ int sSlotRowF[EB];

  int* s_srow = sShare;
  float* sPart = (float*)sShare;

  int t = threadIdx.x;
  sW1t[t] = W1t[t];
  if (t < 64) { sb1v[t] = b1[t]; sb2v[t] = b2[t]; }
  if (COORD && t >= 64 && t < 128) { scb1v[t - 64] = cb1[t - 64]; scW2v[t - 64] = cW2[t - 64]; }
  __syncthreads();

  int e0 = blockIdx.x * EB;
  int nE = E - e0; if (nE > EB) nE = EB;

  // ---- stage 1: u tile -> bf16 hi/lo, conflict-free b128 writes ----
#pragma unroll
  for (int p = 0; p < 4; p++) {
    int eloc = p * 32 + (t >> 3);
    int ks = t & 7;
    int e = e0 + eloc;
    int base = eloc * 128 + ks * 16;
    int swz = (eloc & 7) << 4;
    if (e < E) {
      int r = srow[e];
      int c = scol[e];
      float prx = posr[(size_t)r * 3 + 0], pry = posr[(size_t)r * 3 + 1],
            prz = posr[(size_t)r * 3 + 2];
      float pcx = posr[(size_t)c * 3 + 0], pcy = posr[(size_t)c * 3 + 1],
            pcz = posr[(size_t)c * 3 + 2];
      float dx = prx - pcx, dy = pry - pcy, dz = prz - pcz;
      float dist = sqrtf(dx * dx + dy * dy + dz * dz);
      if (ks == 0) {
        s_srow[eloc] = r;
        sDiff[0][eloc] = dx; sDiff[1][eloc] = dy; sDiff[2][eloc] = dz;
      }
      float4 ea = ((const float4*)sea4)[e];
      const float4* P4p = (const float4*)(P + (size_t)r * 64) + ks * 2;
      const float4* Q4p = (const float4*)(Q + (size_t)c * 64) + ks * 2;
      float4 a0 = P4p[0], a1 = P4p[1];
      float4 q0 = Q4p[0], q1 = Q4p[1];
      float pa[8] = {a0.x, a0.y, a0.z, a0.w, a1.x, a1.y, a1.z, a1.w};
      float qa[8] = {q0.x, q0.y, q0.z, q0.w, q1.x, q1.y, q1.z, q1.w};
      ushort hh[8], ll[8];
#pragma unroll
      for (int kk = 0; kk < 8; kk++) {
        int k = ks * 8 + kk;
        float val = pa[kk] + qa[kk] + sb1v[k] + dist * sW1t[k] + ea.x * sW1t[64 + k] +
                    ea.y * sW1t[128 + k] + ea.z * sW1t[192 + k];
        float uv = silu_f(val);
        bf16_split(uv, hh[kk], ll[kk]);
      }
      uint4 hv, lv;
      hv.x = (uint)hh[0] | ((uint)hh[1] << 16);
      hv.y = (uint)hh[2] | ((uint)hh[3] << 16);
      hv.z = (uint)hh[4] | ((uint)hh[5] << 16);
      hv.w = (uint)hh[6] | ((uint)hh[7] << 16);
      lv.x = (uint)ll[0] | ((uint)ll[1] << 16);
      lv.y = (uint)ll[2] | ((uint)ll[3] << 16);
      lv.z = (uint)ll[4] | ((uint)ll[5] << 16);
      lv.w = (uint)ll[6] | ((uint)ll[7] << 16);
      *(uint4*)((char*)sUhi + (base ^ swz)) = hv;
      *(uint4*)((char*)sUlo + (base ^ swz)) = lv;
    } else {
      uint4 z; z.x = 0; z.y = 0; z.z = 0; z.w = 0;
      *(uint4*)((char*)sUhi + (base ^ swz)) = z;
      *(uint4*)((char*)sUlo + (base ^ swz)) = z;
    }
  }
  __syncthreads();

  // ---- phase A: slot ballot ----
  bool isstart = false;
  int pre = 0;
  if (t < 128) {
    int le = t;
    isstart = (le < nE) && (le == 0 || s_srow[le] != s_srow[le - 1]);
    unsigned long long m = __ballot(isstart ? 1 : 0);
    int lane = t & 63;
    pre = __popcll(m & ((lane == 0) ? 0ull : ((~0ull) >> (64 - lane))));
    if (lane == 0) sSlotCnt[t >> 6] = __popcll(m);
  }
  __syncthreads();
  if (t < 128 && isstart) {
    int le = t;
    int slot = ((t >> 6) ? sSlotCnt[0] : 0) + pre;
    int row = s_srow[le];
    sSlotStart[slot] = le;
    int rs = rowptr[row], re = rowptr[row + 1];
    int interior = (rs >= e0 && re <= e0 + nE) ? 1 : 0;
    sSlotRowF[slot] = row | (interior << 30);
  }
  if (t == 0) sSlotStart[sSlotCnt[0] + sSlotCnt[1]] = nE;
  // published by stage-2's internal barrier

  // ---- stage 2: m^T = W2^T · u^T ----
  int l = t & 63;
  int wv = t >> 6;
  int lane16 = l & 15;
  int kq = l >> 4;

  {
    const ushort* bhp = w2h + (wv * 16 + lane16) * 64 + kq * 8;
    const ushort* blp = w2l + (wv * 16 + lane16) * 64 + kq * 8;
    bshort8 wh0 = *(const bshort8*)(bhp);
    bshort8 wh1 = *(const bshort8*)(bhp + 32);
    bshort8 wl0 = *(const bshort8*)(blp);
    bshort8 wl1 = *(const bshort8*)(blp + 32);

    f32x4 acc[8];
#pragma unroll
    for (int et = 0; et < 8; et++) {
      int edge = et * 16 + lane16;
      bshort8 uh0 = lds_frag(sUhi, edge, kq * 8);
      bshort8 uh1 = lds_frag(sUhi, edge, 32 + kq * 8);
      bshort8 ul0 = lds_frag(sUlo, edge, kq * 8);
      bshort8 ul1 = lds_frag(sUlo, edge, 32 + kq * 8);
      f32x4 a = {0.f, 0.f, 0.f, 0.f};
      a = __builtin_amdgcn_mfma_f32_16x16x32_bf16(wh0, uh0, a, 0, 0, 0);
      a = __builtin_amdgcn_mfma_f32_16x16x32_bf16(wh1, uh1, a, 0, 0, 0);
      a = __builtin_amdgcn_mfma_f32_16x16x32_bf16(wh0, ul0, a, 0, 0, 0);
      a = __builtin_amdgcn_mfma_f32_16x16x32_bf16(wh1, ul1, a, 0, 0, 0);
      a = __builtin_amdgcn_mfma_f32_16x16x32_bf16(wl0, uh0, a, 0, 0, 0);
      a = __builtin_amdgcn_mfma_f32_16x16x32_bf16(wl1, uh1, a, 0, 0, 0);
      acc[et] = a;
    }
    __syncthreads();  // all u reads done; slot tables published

    float b2r[4];
#pragma unroll
    for (int r = 0; r < 4; r++) b2r[r] = sb2v[wv * 16 + kq * 4 + r];
#pragma unroll
    for (int et = 0; et < 8; et++) {
      int edge = et * 16 + lane16;
      ushort mh[4], ml[4];
#pragma unroll
      for (int r = 0; r < 4; r++) {
        float mv = silu_f(acc[et][r] + b2r[r]);
        bf16_split(mv, mh[r], ml[r]);
      }
      int byte = (edge * 128 + (wv * 16 + kq * 4) * 2) ^ ((edge & 7) << 4);
      uint2 hv, lv;
      hv.x = (uint)mh[0] | ((uint)mh[1] << 16);
      hv.y = (uint)mh[2] | ((uint)mh[3] << 16);
      lv.x = (uint)ml[0] | ((uint)ml[1] << 16);
      lv.y = (uint)ml[2] | ((uint)ml[3] << 16);
      *(uint2*)((char*)sUhi + byte) = hv;
      *(uint2*)((char*)sUlo + byte) = lv;
    }
  }
  __syncthreads();

  int nslots = sSlotCnt[0] + sSlotCnt[1];

  if (COORD) {
    // ---- wave-specialized: waves 0-1 agg scan || waves 2-3 stage-3 ----
    if (wv >= 2) {
#pragma unroll
      for (int cg2 = 0; cg2 < 2; cg2++) {
        int colg = (wv - 2) * 2 + cg2;  // 0..3
        int colb = colg * 16;
        const ushort* chp = c1h + (colb + lane16) * 64 + kq * 8;
        const ushort* clp = c1l + (colb + lane16) * 64 + kq * 8;
        bshort8 ch0 = *(const bshort8*)(chp);
        bshort8 ch1 = *(const bshort8*)(chp + 32);
        bshort8 cl0 = *(const bshort8*)(clp);
        bshort8 cl1 = *(const bshort8*)(clp + 32);
        float cb1r[4], cw2r[4];
#pragma unroll
        for (int r = 0; r < 4; r++) {
          cb1r[r] = scb1v[colb + kq * 4 + r];
          cw2r[r] = scW2v[colb + kq * 4 + r];
        }
#pragma unroll
        for (int et = 0; et < 8; et++) {
          int edge = et * 16 + lane16;
          bshort8 mh0 = lds_frag(sUhi, edge, kq * 8);
          bshort8 mh1 = lds_frag(sUhi, edge, 32 + kq * 8);
          f32x4 a = {0.f, 0.f, 0.f, 0.f};
          a = __builtin_amdgcn_mfma_f32_16x16x32_bf16(ch0, mh0, a, 0, 0, 0);
          a = __builtin_amdgcn_mfma_f32_16x16x32_bf16(ch1, mh1, a, 0, 0, 0);
          a = __builtin_amdgcn_mfma_f32_16x16x32_bf16(cl0, mh0, a, 0, 0, 0);
          a = __builtin_amdgcn_mfma_f32_16x16x32_bf16(cl1, mh1, a, 0, 0, 0);
          float pr = 0.f;
#pragma unroll
          for (int r = 0; r < 4; r++) pr += silu_f(a[r] + cb1r[r]) * cw2r[r];
          pr += __shfl_xor(pr, 16);
          pr += __shfl_xor(pr, 32);
          if (kq == 0) sPart[edge * 4 + colg] = pr;
        }
      }
    } else {
      // agg scan on waves 0-1 (stride 128)
      for (int task = t; task < (nslots << 5); task += 128) {
        int s = task >> 5, cp = task & 31;
        int a = sSlotStart[s], b = sSlotStart[s + 1];
        float acc0 = 0.f, acc1 = 0.f;
        for (int le = a; le < b; le++) {
          int byte = (le * 128 + cp * 4) ^ ((le & 7) << 4);
          uint hv = *(const uint*)((const char*)sUhi + byte);
          uint lv = *(const uint*)((const char*)sUlo + byte);
          acc0 += __uint_as_float(hv << 16) + __uint_as_float(lv << 16);
          acc1 += __uint_as_float(hv & 0xffff0000u) + __uint_as_float(lv & 0xffff0000u);
        }
        int rowf = sSlotRowF[s];
        int row = rowf & 0x3fffffff;
        float* ap = agg + (size_t)row * 64 + 2 * cp;
        if (rowf & (1 << 30)) {
          ap[0] = acc0; ap[1] = acc1;
        } else {
          atomicAdd(ap, acc0);
          atomicAdd(ap + 1, acc1);
        }
      }
    }
    __syncthreads();
    if (t < 128) {
      int e = t;
      sWe[e] = sPart[4 * e + 0] + sPart[4 * e + 1] + sPart[4 * e + 2] + sPart[4 * e + 3] + cb2[0];
    }
    __syncthreads();
    // pos reduce (small: nslots*3 tasks)
    for (int task = t; task < (nslots << 2); task += 256) {
      int s = task >> 2, d = task & 3;
      if (d < 3) {
        int a = sSlotStart[s], b = sSlotStart[s + 1];
        float acc = 0.f;
        for (int le = a; le < b; le++) acc += sDiff[d][le] * sWe[le];
        int row = sSlotRowF[s] & 0x3fffffff;
        atomicAdd(&posw[(size_t)row * 3 + d], acc);
      }
    }
  } else {
    // non-COORD: agg scan on all 4 waves
    for (int task = t; task < (nslots << 5); task += 256) {
      int s = task >> 5, cp = task & 31;
      int a = sSlotStart[s], b = sSlotStart[s + 1];
      float acc0 = 0.f, acc1 = 0.f;
      for (int le = a; le < b; le++) {
        int byte = (le * 128 + cp * 4) ^ ((le & 7) << 4);
        uint hv = *(const uint*)((const char*)sUhi + byte);
        uint lv = *(const uint*)((const char*)sUlo + byte);
        acc0 += __uint_as_float(hv << 16) + __uint_as_float(lv << 16);
        acc1 += __uint_as_float(hv & 0xffff0000u) + __uint_as_float(lv & 0xffff0000u);
      }
      int rowf = sSlotRowF[s];
      int row = rowf & 0x3fffffff;
      float* ap = agg + (size_t)row * 64 + 2 * cp;
      if (rowf & (1 << 30)) {
        ap[0] = acc0; ap[1] = acc1;
      } else {
        atomicAdd(ap, acc0);
        atomicAdd(ap + 1, acc1);
      }
    }
  }
}

// ---------------- pooling + classifier ----------------
__device__ __forceinline__ int lbound(const int* __restrict__ a, int n, int v)
{
  int lo = 0, hi = n;
  while (lo < hi) {
    int mid = (lo + hi) >> 1;
    if (a[mid] < v) lo = mid + 1;
    else hi = mid;
  }
  return lo;
}

__global__ __launch_bounds__(256) void pool_cls_kernel(
    const float* __restrict__ h, const int* __restrict__ batch, int N,
    const float* __restrict__ W1, const float* __restrict__ b1,
    const float* __restrict__ W2, const float* __restrict__ b2, float* __restrict__ out)
{
  int g = blockIdx.x;
  int start = lbound(batch, N, g);
  int end = lbound(batch, N, g + 1);
  int j = threadIdx.x & 63;
  int grp = threadIdx.x >> 6;
  float s = 0.f, mx = -INFINITY;
  for (int n = start + grp; n < end; n += 4) {
    float v = h[(size_t)n * 64 + j];
    s += v;
    mx = fmaxf(mx, v);
  }
  __shared__ float ssum[4][64];
  __shared__ float smax[4][64];
  __shared__ float pooled[128];
  __shared__ float su[64];
  ssum[grp][j] = s;
  smax[grp][j] = mx;
  __syncthreads();
  if (grp == 0) {
    float S = ssum[0][j] + ssum[1][j] + ssum[2][j] + ssum[3][j];
    float M = fmaxf(fmaxf(smax[0][j], smax[1][j]), fmaxf(smax[2][j], smax[3][j]));
    float cnt = (float)(end - start);
    pooled[j] = S / fmaxf(cnt, 1.0f);
    pooled[64 + j] = M;
  }
  __syncthreads();
  if (threadIdx.x < 64) {
    float a = b1[j];
#pragma unroll
    for (int k = 0; k < 128; k++) a += pooled[k] * W1[k * 64 + j];
    su[j] = fmaxf(a, 0.f);
  }
  __syncthreads();
  if (threadIdx.x < 2) {
    float a = b2[threadIdx.x];
#pragma unroll
    for (int k = 0; k < 64; k++) a += su[k] * W2[k * 2 + threadIdx.x];
    out[g * 2 + threadIdx.x] = a;
  }
}

extern "C" void kernel_launch(void* const* d_in, const int* in_sizes, int n_in,
                              void* d_out, int out_size, void* d_ws, size_t ws_size,
                              hipStream_t stream)
{
  const float* x = (const float*)d_in[0];
  const float* pos = (const float*)d_in[1];
  const int* ei = (const int*)d_in[2];
  const float* eattr = (const float*)d_in[3];
  const int* batch = (const int*)d_in[4];
  const float* projW = (const float*)d_in[5];
  const float* projb = (const float*)d_in[6];
  const float* msgW1 = (const float*)d_in[7];
  const float* msgb1 = (const float*)d_in[8];
  const float* msgW2 = (const float*)d_in[9];
  const float* msgb2 = (const float*)d_in[10];
  const float* ndW1 = (const float*)d_in[11];
  const float* ndb1 = (const float*)d_in[12];
  const float* ndW2 = (const float*)d_in[13];
  const float* ndb2 = (const float*)d_in[14];
  const float* cdW1 = (const float*)d_in[15];
  const float* cdb1 = (const float*)d_in[16];
  const float* cdW2 = (const float*)d_in[17];
  const float* cdb2 = (const float*)d_in[18];
  const float* clsW1 = (const float*)d_in[19];
  const float* clsb1 = (const float*)d_in[20];
  const float* clsW2 = (const float*)d_in[21];
  const float* clsb2 = (const float*)d_in[22];

  int N = in_sizes[4];
  int E = in_sizes[3] / 3;
  const int* rowp = ei;
  const int* colp = ei + E;

  char* wsb = (char*)d_ws;
  size_t off = 0;
  auto alloc = [&](size_t bytes) {
    size_t o = off;
    off = (off + bytes + 255) & ~(size_t)255;
    return o;
  };
  size_t nh = (size_t)N * 64 * sizeof(float);
  size_t o_h = alloc(nh);
  size_t o_P = alloc(nh);
  size_t o_Q = alloc(nh);
  size_t o_agg = alloc(nh);
  size_t o_posA = alloc((size_t)N * 3 * sizeof(float));
  size_t o_posB = alloc((size_t)N * 3 * sizeof(float));
  size_t o_cnt = alloc((size_t)N * sizeof(int));
  size_t o_rowptr = alloc(((size_t)N + 1) * sizeof(int));
  size_t o_cursor = alloc((size_t)N * sizeof(int));
  size_t o_srow = alloc((size_t)E * sizeof(int));
  size_t o_scol = alloc((size_t)E * sizeof(int));
  size_t o_sea4 = alloc((size_t)E * 4 * sizeof(float));
  size_t o_w2h = alloc(4 * 4096 * sizeof(ushort));
  size_t o_w2l = alloc(4 * 4096 * sizeof(ushort));
  size_t o_c1h = alloc(4 * 4096 * sizeof(ushort));
  size_t o_c1l = alloc(4 * 4096 * sizeof(ushort));
  size_t o_n1h = alloc(4 * 8192 * sizeof(ushort));
  size_t o_n1l = alloc(4 * 8192 * sizeof(ushort));
  size_t o_n2h = alloc(4 * 4096 * sizeof(ushort));
  size_t o_n2l = alloc(4 * 4096 * sizeof(ushort));
  size_t o_pqh = alloc(4 * 8192 * sizeof(ushort));
  size_t o_pql = alloc(4 * 8192 * sizeof(ushort));
  size_t csr_end = off;

  float* h = (float*)(wsb + o_h);
  float* Pb = (float*)(wsb + o_P);
  float* Qb = (float*)(wsb + o_Q);
  float* agg = (float*)(wsb + o_agg);
  float* posA = (float*)(wsb + o_posA);
  float* posB = (float*)(wsb + o_posB);

  int nb_nodes = (N + 255) / 256;
  int nb_edges = (E + 255) / 256;
  int nb_tiled = (N + EB - 1) / EB;
  int G = out_size / 2;

  proj_kernel<<<nb_nodes, 256, 0, stream>>>(x, projW, projb, h, N);

  const float* pr[4] = {pos, posA, posB, posA};
  float* pw[4] = {posA, posB, posA, nullptr};

  bool use_sorted = (csr_end <= ws_size);

  if (use_sorted) {
    int* cnt = (int*)(wsb + o_cnt);
    int* rowptr = (int*)(wsb + o_rowptr);
    int* cursor = (int*)(wsb + o_cursor);
    int* srow = (int*)(wsb + o_srow);
    int* scol = (int*)(wsb + o_scol);
    float* sea4 = (float*)(wsb + o_sea4);
    ushort* w2h = (ushort*)(wsb + o_w2h);
    ushort* w2l = (ushort*)(wsb + o_w2l);
    ushort* c1h = (ushort*)(wsb + o_c1h);
    ushort* c1l = (ushort*)(wsb + o_c1l);
    ushort* n1h = (ushort*)(wsb + o_n1h);
    ushort* n1l = (ushort*)(wsb + o_n1l);
    ushort* n2h = (ushort*)(wsb + o_n2h);
    ushort* n2l = (ushort*)(wsb + o_n2l);
    ushort* pqh = (ushort*)(wsb + o_pqh);
    ushort* pql = (ushort*)(wsb + o_pql);

    hipMemsetAsync(cnt, 0, (size_t)N * sizeof(int), stream);
    hist_kernel<<<nb_edges, 256, 0, stream>>>(rowp, cnt, E);
    scan_kernel<<<1, 1024, 0, stream>>>(cnt, rowptr, cursor, N, E);
    scatter_kernel<<<nb_edges, 256, 0, stream>>>(rowp, colp, eattr, cursor, srow, scol, sea4, E);
    prep_wt_kernel<<<64, 256, 0, stream>>>(msgW2, cdW1, w2h, w2l, c1h, c1l);
    prep_nd_kernel<<<128, 256, 0, stream>>>(ndW1, ndW2, msgW1, n1h, n1l, n2h, n2l, pqh, pql);

    premul_mfma_kernel<<<nb_tiled, 256, 0, stream>>>(h, pqh, pql, Pb, Qb, N);

    int nb_fused = (E + EB - 1) / EB;
    for (int i = 0; i < 4; i++) {
      hipMemsetAsync(agg, 0, nh, stream);
      if (i < 3) {
        hipMemcpyAsync(pw[i], pr[i], (size_t)N * 3 * sizeof(float), hipMemcpyDeviceToDevice,
                       stream);
        edge_fused_kernel<1><<<nb_fused, 256, 0, stream>>>(
            srow, scol, rowptr, pr[i], pw[i], sea4, Pb, Qb,
            msgW1 + (size_t)i * 132 * 64 + 128 * 64, msgb1 + i * 64,
            w2h + (size_t)i * 4096, w2l + (size_t)i * 4096, msgb2 + i * 64,
            c1h + (size_t)i * 4096, c1l + (size_t)i * 4096,
            cdb1 + i * 64, cdW2 + i * 64, cdb2 + i, agg, E);
        node_mfma_kernel<1><<<nb_tiled, 256, 0, stream>>>(
            h, agg, n1h + (size_t)i * 8192, n1l + (size_t)i * 8192, ndb1 + i * 64,
            n2h + (size_t)i * 4096, n2l + (size_t)i * 4096, ndb2 + i * 64,
            pqh + (size_t)(i + 1) * 8192, pql + (size_t)(i + 1) * 8192, Pb, Qb, N);
      } else {
        edge_fused_kernel<0><<<nb_fused, 256, 0, stream>>>(
            srow, scol, rowptr, pr[i], nullptr, sea4, Pb, Qb,
            msgW1 + (size_t)i * 132 * 64 + 128 * 64, msgb1 + i * 64,
            w2h + (size_t)i * 4096, w2l + (size_t)i * 4096, msgb2 + i * 64,
            nullptr, nullptr, nullptr, nullptr, nullptr, agg, E);
        node_mfma_kernel<0><<<nb_tiled, 256, 0, stream>>>(
            h, agg, n1h + (size_t)i * 8192, n1l + (size_t)i * 8192, ndb1 + i * 64,
            n2h + (size_t)i * 4096, n2l + (size_t)i * 4096, ndb2 + i * 64,
            nullptr, nullptr, nullptr, nullptr, N);
      }
    }
  }

  pool_cls_kernel<<<G, 256, 0, stream>>>(h, batch, N, clsW1, clsb1, clsW2, clsb2, (float*)d_out);
}

// Round 16
// 796.249 us; speedup vs baseline: 1.0786x; 1.0786x over previous
//
#include <hip/hip_runtime.h>
#include <math.h>

// EGNN forward. P/Q factorization + CSR sort + fused MFMA edge kernel.
// Round 16: revert to round-14 state (best measured: 796us). Round 15's
// wave-specialized epilogue regressed (VGPR 56->76, occupancy 38->30%,
// 2-wave stage-3 serialization) and is dropped.

typedef __attribute__((ext_vector_type(8))) short bshort8;
typedef __attribute__((ext_vector_type(4))) float f32x4;
typedef unsigned short ushort;
typedef unsigned int uint;

__device__ __forceinline__ float silu_f(float x)
{
  return x * __builtin_amdgcn_rcpf(1.0f + __expf(-x));
}

__device__ __forceinline__ void bf16_split(float x, ushort& h, ushort& l)
{
  uint bx = __float_as_uint(x);
  ushort hb = (ushort)(bx >> 16);
  float hf = __uint_as_float((uint)hb << 16);
  float r = x - hf;
  l = (ushort)(__float_as_uint(r) >> 16);
  h = hb;
}

#define ROW_FMA(acc, scal, rowptr)                                                   \
  {                                                                                  \
    const float4* _w = (const float4*)(rowptr);                                      \
    _Pragma("unroll") for (int _j = 0; _j < 16; _j++)                                \
    {                                                                                \
      float4 _wv = _w[_j];                                                           \
      acc[4 * _j + 0] += (scal) * _wv.x;                                             \
      acc[4 * _j + 1] += (scal) * _wv.y;                                             \
      acc[4 * _j + 2] += (scal) * _wv.z;                                             \
      acc[4 * _j + 3] += (scal) * _wv.w;                                             \
    }                                                                                \
  }

// ---------------- proj ----------------
__global__ __launch_bounds__(256) void proj_kernel(
    const float* __restrict__ x, const float* __restrict__ W, const float* __restrict__ b,
    float* __restrict__ h, int N)
{
  __shared__ float sW[26 * 64];
  __shared__ float sb[64];
  for (int i = threadIdx.x; i < 26 * 64; i += 256) sW[i] = W[i];
  if (threadIdx.x < 64) sb[threadIdx.x] = b[threadIdx.x];
  __syncthreads();
  int n = blockIdx.x * 256 + threadIdx.x;
  if (n >= N) return;
  float acc[64];
#pragma unroll
  for (int j = 0; j < 64; j++) acc[j] = sb[j];
#pragma unroll
  for (int k = 0; k < 26; k++) {
    float xk = x[(size_t)n * 26 + k];
    ROW_FMA(acc, xk, sW + k * 64);
  }
  float4* h4 = (float4*)(h + (size_t)n * 64);
#pragma unroll
  for (int j4 = 0; j4 < 16; j4++) {
    float4 v;
    v.x = acc[4 * j4 + 0]; v.y = acc[4 * j4 + 1]; v.z = acc[4 * j4 + 2]; v.w = acc[4 * j4 + 3];
    h4[j4] = v;
  }
}

// ---------------- shared helpers for MFMA tile kernels ----------------
#define EB 128

__device__ __forceinline__ bshort8 lds_frag(const ushort* base, int edge, int kb)
{
  int byte = edge * 128 + kb * 2;
  byte ^= (edge & 7) << 4;
  return *(const bshort8*)((const char*)base + byte);
}

// stage a [128][64] fp32 tile -> bf16 hi/lo XOR-swizzled LDS (conflict-free b128)
__device__ __forceinline__ void stage_tile_f32(
    const float* __restrict__ src, int n0, int N, ushort* sHi, ushort* sLo, int t)
{
#pragma unroll
  for (int p = 0; p < 4; p++) {
    int nl = p * 32 + (t >> 3);
    int ks = t & 7;
    int n = n0 + nl;
    int base = nl * 128 + ks * 16;
    int swz = (nl & 7) << 4;
    if (n < N) {
      const float4* sp = (const float4*)(src + (size_t)n * 64) + ks * 2;
      float4 a0 = sp[0], a1 = sp[1];
      float va[8] = {a0.x, a0.y, a0.z, a0.w, a1.x, a1.y, a1.z, a1.w};
      ushort hh[8], ll[8];
#pragma unroll
      for (int kk = 0; kk < 8; kk++) bf16_split(va[kk], hh[kk], ll[kk]);
      uint4 hv, lv;
      hv.x = (uint)hh[0] | ((uint)hh[1] << 16);
      hv.y = (uint)hh[2] | ((uint)hh[3] << 16);
      hv.z = (uint)hh[4] | ((uint)hh[5] << 16);
      hv.w = (uint)hh[6] | ((uint)hh[7] << 16);
      lv.x = (uint)ll[0] | ((uint)ll[1] << 16);
      lv.y = (uint)ll[2] | ((uint)ll[3] << 16);
      lv.z = (uint)ll[4] | ((uint)ll[5] << 16);
      lv.w = (uint)ll[6] | ((uint)ll[7] << 16);
      *(uint4*)((char*)sHi + (base ^ swz)) = hv;
      *(uint4*)((char*)sLo + (base ^ swz)) = lv;
    } else {
      uint4 z; z.x = 0; z.y = 0; z.z = 0; z.w = 0;
      *(uint4*)((char*)sHi + (base ^ swz)) = z;
      *(uint4*)((char*)sLo + (base ^ swz)) = z;
    }
  }
}

// 3-split GEMM panel: acc[et] += Wt(col) · A(node) over one 64-k panel.
#define PANEL_MFMA(accv, bhp, blp, sHi, sLo)                                         \
  {                                                                                  \
    bshort8 wh0 = *(const bshort8*)(bhp);                                            \
    bshort8 wh1 = *(const bshort8*)((bhp) + 32);                                     \
    bshort8 wl0 = *(const bshort8*)(blp);                                            \
    bshort8 wl1 = *(const bshort8*)((blp) + 32);                                     \
    _Pragma("unroll") for (int et = 0; et < 8; et++)                                 \
    {                                                                                \
      int nd = et * 16 + lane16;                                                     \
      bshort8 ah0 = lds_frag(sHi, nd, kq * 8);                                       \
      bshort8 ah1 = lds_frag(sHi, nd, 32 + kq * 8);                                  \
      bshort8 al0 = lds_frag(sLo, nd, kq * 8);                                       \
      bshort8 al1 = lds_frag(sLo, nd, 32 + kq * 8);                                  \
      f32x4 a = accv[et];                                                            \
      a = __builtin_amdgcn_mfma_f32_16x16x32_bf16(wh0, ah0, a, 0, 0, 0);             \
      a = __builtin_amdgcn_mfma_f32_16x16x32_bf16(wh1, ah1, a, 0, 0, 0);             \
      a = __builtin_amdgcn_mfma_f32_16x16x32_bf16(wh0, al0, a, 0, 0, 0);             \
      a = __builtin_amdgcn_mfma_f32_16x16x32_bf16(wh1, al1, a, 0, 0, 0);             \
      a = __builtin_amdgcn_mfma_f32_16x16x32_bf16(wl0, ah0, a, 0, 0, 0);             \
      a = __builtin_amdgcn_mfma_f32_16x16x32_bf16(wl1, ah1, a, 0, 0, 0);             \
      accv[et] = a;                                                                  \
    }                                                                                \
  }

// ---------------- MFMA premul (layer 0): P=h@W1[0:64], Q=h@W1[64:128] ----------------
__global__ __launch_bounds__(256) void premul_mfma_kernel(
    const float* __restrict__ h, const ushort* __restrict__ pqh, const ushort* __restrict__ pql,
    float* __restrict__ P, float* __restrict__ Q, int N)
{
  __shared__ ushort sAhi[EB * 64];
  __shared__ ushort sAlo[EB * 64];
  int t = threadIdx.x;
  int n0 = blockIdx.x * EB;
  stage_tile_f32(h, n0, N, sAhi, sAlo, t);
  __syncthreads();

  int l = t & 63, wv = t >> 6, lane16 = l & 15, kq = l >> 4;
  int col = wv * 16 + kq * 4;

  f32x4 acc[8];
#pragma unroll
  for (int et = 0; et < 8; et++) { f32x4 z = {0.f, 0.f, 0.f, 0.f}; acc[et] = z; }
  {
    const ushort* bh = pqh + (wv * 16 + lane16) * 64 + kq * 8;
    const ushort* bl = pql + (wv * 16 + lane16) * 64 + kq * 8;
    PANEL_MFMA(acc, bh, bl, sAhi, sAlo);
  }
#pragma unroll
  for (int et = 0; et < 8; et++) {
    int n = n0 + et * 16 + lane16;
    if (n < N) {
      float4 v; v.x = acc[et][0]; v.y = acc[et][1]; v.z = acc[et][2]; v.w = acc[et][3];
      *(float4*)(P + (size_t)n * 64 + col) = v;
    }
  }
#pragma unroll
  for (int et = 0; et < 8; et++) { f32x4 z = {0.f, 0.f, 0.f, 0.f}; acc[et] = z; }
  {
    const ushort* bh = pqh + 4096 + (wv * 16 + lane16) * 64 + kq * 8;
    const ushort* bl = pql + 4096 + (wv * 16 + lane16) * 64 + kq * 8;
    PANEL_MFMA(acc, bh, bl, sAhi, sAlo);
  }
#pragma unroll
  for (int et = 0; et < 8; et++) {
    int n = n0 + et * 16 + lane16;
    if (n < N) {
      float4 v; v.x = acc[et][0]; v.y = acc[et][1]; v.z = acc[et][2]; v.w = acc[et][3];
      *(float4*)(Q + (size_t)n * 64 + col) = v;
    }
  }
}

// ---------------- MFMA node MLP (+fused premul for next layer) ----------------
template <int PREMUL>
__global__ __launch_bounds__(256) void node_mfma_kernel(
    float* __restrict__ h, const float* __restrict__ agg,
    const ushort* __restrict__ n1h, const ushort* __restrict__ n1l,  // [col][128]
    const float* __restrict__ b1,
    const ushort* __restrict__ n2h, const ushort* __restrict__ n2l,  // [col][64]
    const float* __restrict__ b2,
    const ushort* __restrict__ pqh, const ushort* __restrict__ pql,  // next layer [2][col][64]
    float* __restrict__ P, float* __restrict__ Q, int N)
{
  __shared__ ushort sAhi[EB * 64];
  __shared__ ushort sAlo[EB * 64];
  __shared__ float sb1v[64], sb2v[64];
  int t = threadIdx.x;
  int n0 = blockIdx.x * EB;
  if (t < 64) { sb1v[t] = b1[t]; sb2v[t] = b2[t]; }

  stage_tile_f32(h, n0, N, sAhi, sAlo, t);
  __syncthreads();

  int l = t & 63, wv = t >> 6, lane16 = l & 15, kq = l >> 4;
  int col = wv * 16 + kq * 4;

  // u = silu([h,agg]@W1 + b1): panel 1 (h, k 0..63)
  f32x4 acc[8];
#pragma unroll
  for (int et = 0; et < 8; et++) { f32x4 z = {0.f, 0.f, 0.f, 0.f}; acc[et] = z; }
  {
    const ushort* bh = n1h + (wv * 16 + lane16) * 128 + kq * 8;
    const ushort* bl = n1l + (wv * 16 + lane16) * 128 + kq * 8;
    PANEL_MFMA(acc, bh, bl, sAhi, sAlo);
  }
  __syncthreads();  // done reading h tile
  stage_tile_f32(agg, n0, N, sAhi, sAlo, t);
  __syncthreads();
  // panel 2 (agg, k 64..127)
  {
    const ushort* bh = n1h + (wv * 16 + lane16) * 128 + 64 + kq * 8;
    const ushort* bl = n1l + (wv * 16 + lane16) * 128 + 64 + kq * 8;
    PANEL_MFMA(acc, bh, bl, sAhi, sAlo);
  }
  __syncthreads();  // done reading agg tile

  // u writeback (packed, swizzled)
  {
    float b1r[4];
#pragma unroll
    for (int r = 0; r < 4; r++) b1r[r] = sb1v[col + r];
#pragma unroll
    for (int et = 0; et < 8; et++) {
      int nd = et * 16 + lane16;
      ushort uh[4], ul[4];
#pragma unroll
      for (int r = 0; r < 4; r++) {
        float uv = silu_f(acc[et][r] + b1r[r]);
        bf16_split(uv, uh[r], ul[r]);
      }
      int byte = (nd * 128 + col * 2) ^ ((nd & 7) << 4);
      uint2 hv, lv;
      hv.x = (uint)uh[0] | ((uint)uh[1] << 16);
      hv.y = (uint)uh[2] | ((uint)uh[3] << 16);
      lv.x = (uint)ul[0] | ((uint)ul[1] << 16);
      lv.y = (uint)ul[2] | ((uint)ul[3] << 16);
      *(uint2*)((char*)sAhi + byte) = hv;
      *(uint2*)((char*)sAlo + byte) = lv;
    }
  }
  __syncthreads();

  // o = u @ W2 ; hnew = h + o + b2
#pragma unroll
  for (int et = 0; et < 8; et++) { f32x4 z = {0.f, 0.f, 0.f, 0.f}; acc[et] = z; }
  {
    const ushort* bh = n2h + (wv * 16 + lane16) * 64 + kq * 8;
    const ushort* bl = n2l + (wv * 16 + lane16) * 64 + kq * 8;
    PANEL_MFMA(acc, bh, bl, sAhi, sAlo);
  }
  uint2 hnh[8], hnl[8];  // packed hnew for PREMUL tile write
  {
    float b2r[4];
#pragma unroll
    for (int r = 0; r < 4; r++) b2r[r] = sb2v[col + r];
#pragma unroll
    for (int et = 0; et < 8; et++) {
      int n = n0 + et * 16 + lane16;
      float hn[4];
      if (n < N) {
        float4 hv = *(float4*)(h + (size_t)n * 64 + col);
        hn[0] = hv.x + acc[et][0] + b2r[0];
        hn[1] = hv.y + acc[et][1] + b2r[1];
        hn[2] = hv.z + acc[et][2] + b2r[2];
        hn[3] = hv.w + acc[et][3] + b2r[3];
        float4 sv; sv.x = hn[0]; sv.y = hn[1]; sv.z = hn[2]; sv.w = hn[3];
        *(float4*)(h + (size_t)n * 64 + col) = sv;
      } else {
        hn[0] = hn[1] = hn[2] = hn[3] = 0.f;
      }
      if (PREMUL) {
        ushort sh[4], sl[4];
#pragma unroll
        for (int r = 0; r < 4; r++) bf16_split(hn[r], sh[r], sl[r]);
        hnh[et].x = (uint)sh[0] | ((uint)sh[1] << 16);
        hnh[et].y = (uint)sh[2] | ((uint)sh[3] << 16);
        hnl[et].x = (uint)sl[0] | ((uint)sl[1] << 16);
        hnl[et].y = (uint)sl[2] | ((uint)sl[3] << 16);
      }
    }
  }

  if (PREMUL) {
    __syncthreads();  // done reading u tile
#pragma unroll
    for (int et = 0; et < 8; et++) {
      int nd = et * 16 + lane16;
      int byte = (nd * 128 + col * 2) ^ ((nd & 7) << 4);
      *(uint2*)((char*)sAhi + byte) = hnh[et];
      *(uint2*)((char*)sAlo + byte) = hnl[et];
    }
    __syncthreads();
    // P = hnew @ W1n[0:64]
#pragma unroll
    for (int et = 0; et < 8; et++) { f32x4 z = {0.f, 0.f, 0.f, 0.f}; acc[et] = z; }
    {
      const ushort* bh = pqh + (wv * 16 + lane16) * 64 + kq * 8;
      const ushort* bl = pql + (wv * 16 + lane16) * 64 + kq * 8;
      PANEL_MFMA(acc, bh, bl, sAhi, sAlo);
    }
#pragma unroll
    for (int et = 0; et < 8; et++) {
      int n = n0 + et * 16 + lane16;
      if (n < N) {
        float4 v; v.x = acc[et][0]; v.y = acc[et][1]; v.z = acc[et][2]; v.w = acc[et][3];
        *(float4*)(P + (size_t)n * 64 + col) = v;
      }
    }
    // Q = hnew @ W1n[64:128]
#pragma unroll
    for (int et = 0; et < 8; et++) { f32x4 z = {0.f, 0.f, 0.f, 0.f}; acc[et] = z; }
    {
      const ushort* bh = pqh + 4096 + (wv * 16 + lane16) * 64 + kq * 8;
      const ushort* bl = pql + 4096 + (wv * 16 + lane16) * 64 + kq * 8;
      PANEL_MFMA(acc, bh, bl, sAhi, sAlo);
    }
#pragma unroll
    for (int et = 0; et < 8; et++) {
      int n = n0 + et * 16 + lane16;
      if (n < N) {
        float4 v; v.x = acc[et][0]; v.y = acc[et][1]; v.z = acc[et][2]; v.w = acc[et][3];
        *(float4*)(Q + (size_t)n * 64 + col) = v;
      }
    }
  }
}

// ---------------- CSR build ----------------
__global__ __launch_bounds__(256) void hist_kernel(
    const int* __restrict__ row, int* __restrict__ cnt, int E)
{
  int e = blockIdx.x * 256 + threadIdx.x;
  if (e < E) atomicAdd(&cnt[row[e]], 1);
}

__global__ __launch_bounds__(1024) void scan_kernel(
    const int* __restrict__ cnt, int* __restrict__ rowptr, int* __restrict__ cursor, int N, int E)
{
  __shared__ int part[1024];
  int t = threadIdx.x;
  int chunk = (N + 1023) >> 10;
  int lo = t * chunk;
  int hi = lo + chunk;
  if (lo > N) lo = N;
  if (hi > N) hi = N;
  int s = 0;
  for (int i = lo; i < hi; i++) s += cnt[i];
  part[t] = s;
  __syncthreads();
  for (int off = 1; off < 1024; off <<= 1) {
    int v = 0;
    if (t >= off) v = part[t - off];
    __syncthreads();
    if (t >= off) part[t] += v;
    __syncthreads();
  }
  int run = part[t] - s;
  for (int i = lo; i < hi; i++) {
    rowptr[i] = run;
    cursor[i] = run;
    run += cnt[i];
  }
  if (t == 0) rowptr[N] = E;
}

__global__ __launch_bounds__(256) void scatter_kernel(
    const int* __restrict__ row, const int* __restrict__ col, const float* __restrict__ eattr,
    int* __restrict__ cursor, int* __restrict__ srow, int* __restrict__ scol,
    float* __restrict__ sea4, int E)
{
  int e = blockIdx.x * 256 + threadIdx.x;
  if (e >= E) return;
  int r = row[e];
  int p = atomicAdd(&cursor[r], 1);
  srow[p] = r;
  scol[p] = col[e];
  float4 v;
  v.x = eattr[(size_t)e * 3 + 0];
  v.y = eattr[(size_t)e * 3 + 1];
  v.z = eattr[(size_t)e * 3 + 2];
  v.w = 0.f;
  ((float4*)sea4)[p] = v;
}

// ---------------- weight prep: bf16 hi/lo transposed tables ----------------
__global__ __launch_bounds__(256) void prep_wt_kernel(
    const float* __restrict__ W2all, const float* __restrict__ C1all,
    ushort* __restrict__ w2h, ushort* __restrict__ w2l,
    ushort* __restrict__ c1h, ushort* __restrict__ c1l)
{
  int idx = blockIdx.x * 256 + threadIdx.x;
  if (idx >= 4 * 4096) return;
  int layer = idx >> 12, rem = idx & 4095;
  int k = rem >> 6, c = rem & 63;
  int oidx = layer * 4096 + c * 64 + k;
  ushort h, l;
  bf16_split(W2all[idx], h, l);
  w2h[oidx] = h; w2l[oidx] = l;
  if (layer < 3) {
    bf16_split(C1all[idx], h, l);
    c1h[oidx] = h; c1l[oidx] = l;
  }
}

__global__ __launch_bounds__(256) void prep_nd_kernel(
    const float* __restrict__ ndW1, const float* __restrict__ ndW2,
    const float* __restrict__ msgW1,
    ushort* __restrict__ n1h, ushort* __restrict__ n1l,
    ushort* __restrict__ n2h, ushort* __restrict__ n2l,
    ushort* __restrict__ pqh, ushort* __restrict__ pql)
{
  int idx = blockIdx.x * 256 + threadIdx.x;
  if (idx < 4 * 8192) {
    // ndW1[i][k][c], k<128 -> n1[i][c*128+k]
    int i = idx >> 13, rem = idx & 8191;
    int k = rem >> 6, c = rem & 63;
    ushort h, l;
    bf16_split(ndW1[idx], h, l);
    int o = i * 8192 + c * 128 + k;
    n1h[o] = h; n1l[o] = l;
  }
  if (idx < 4 * 4096) {
    int i = idx >> 12, rem = idx & 4095;
    int k = rem >> 6, c = rem & 63;
    ushort h, l;
    bf16_split(ndW2[idx], h, l);
    int o = i * 4096 + c * 64 + k;
    n2h[o] = h; n2l[o] = l;
  }
  if (idx < 4 * 8192) {
    // msgW1[i] rows 0..127 -> pq[i][k>=64][c*64+k%64]
    int i = idx >> 13, rem = idx & 8191;
    int k = rem >> 6, c = rem & 63;
    ushort h, l;
    bf16_split(msgW1[(size_t)i * 132 * 64 + k * 64 + c], h, l);
    int o = i * 8192 + (k >> 6) * 4096 + c * 64 + (k & 63);
    pqh[o] = h; pql[o] = l;
  }
}

// ---------------- fused edge kernel ----------------
template <int COORD>
__global__ __launch_bounds__(256) void edge_fused_kernel(
    const int* __restrict__ srow, const int* __restrict__ scol, const int* __restrict__ rowptr,
    const float* __restrict__ posr, float* __restrict__ posw,
    const float* __restrict__ sea4,
    const float* __restrict__ P, const float* __restrict__ Q,
    const float* __restrict__ W1t, const float* __restrict__ b1,
    const ushort* __restrict__ w2h, const ushort* __restrict__ w2l,
    const float* __restrict__ b2,
    const ushort* __restrict__ c1h, const ushort* __restrict__ c1l,
    const float* __restrict__ cb1, const float* __restrict__ cW2,
    const float* __restrict__ cb2,
    float* __restrict__ agg, int E)
{
  __shared__ ushort sUhi[EB * 64];
  __shared__ ushort sUlo[EB * 64];
  __shared__ float sW1t[4 * 64];
  __shared__ float sb1v[64], sb2v[64];
  __shared__ float sDiff[3][EB];
  __shared__ float sWe[EB];
  __shared__ int sShare[COORD ? EB * 4 : EB];  // s_srow then sPart
  __shared__ float scb1v[COORD ? 64 : 1];
  __shared__ float scW2v[COORD ? 64 : 1];
  __shared__ int sSlotCnt[2];
  __shared__ int sSlotStart[EB + 2];
  __shared__ int sSlotRowF[EB];

  int* s_srow = sShare;
  float* sPart = (float*)sShare;

  int t = threadIdx.x;
  sW1t[t] = W1t[t];
  if (t < 64) { sb1v[t] = b1[t]; sb2v[t] = b2[t]; }
  if (COORD && t >= 64 && t < 128) { scb1v[t - 64] = cb1[t - 64]; scW2v[t - 64] = cW2[t - 64]; }
  __syncthreads();

  int e0 = blockIdx.x * EB;
  int nE = E - e0; if (nE > EB) nE = EB;

  // ---- stage 1: u tile -> bf16 hi/lo, conflict-free b128 writes ----
#pragma unroll
  for (int p = 0; p < 4; p++) {
    int eloc = p * 32 + (t >> 3);
    int ks = t & 7;
    int e = e0 + eloc;
    int base = eloc * 128 + ks * 16;
    int swz = (eloc & 7) << 4;
    if (e < E) {
      int r = srow[e];
      int c = scol[e];
      float prx = posr[(size_t)r * 3 + 0], pry = posr[(size_t)r * 3 + 1],
            prz = posr[(size_t)r * 3 + 2];
      float pcx = posr[(size_t)c * 3 + 0], pcy = posr[(size_t)c * 3 + 1],
            pcz = posr[(size_t)c * 3 + 2];
      float dx = prx - pcx, dy = pry - pcy, dz = prz - pcz;
      float dist = sqrtf(dx * dx + dy * dy + dz * dz);
      if (ks == 0) {
        s_srow[eloc] = r;
        sDiff[0][eloc] = dx; sDiff[1][eloc] = dy; sDiff[2][eloc] = dz;
      }
      float4 ea = ((const float4*)sea4)[e];
      const float4* P4p = (const float4*)(P + (size_t)r * 64) + ks * 2;
      const float4* Q4p = (const float4*)(Q + (size_t)c * 64) + ks * 2;
      float4 a0 = P4p[0], a1 = P4p[1];
      float4 q0 = Q4p[0], q1 = Q4p[1];
      float pa[8] = {a0.x, a0.y, a0.z, a0.w, a1.x, a1.y, a1.z, a1.w};
      float qa[8] = {q0.x, q0.y, q0.z, q0.w, q1.x, q1.y, q1.z, q1.w};
      ushort hh[8], ll[8];
#pragma unroll
      for (int kk = 0; kk < 8; kk++) {
        int k = ks * 8 + kk;
        float val = pa[kk] + qa[kk] + sb1v[k] + dist * sW1t[k] + ea.x * sW1t[64 + k] +
                    ea.y * sW1t[128 + k] + ea.z * sW1t[192 + k];
        float uv = silu_f(val);
        bf16_split(uv, hh[kk], ll[kk]);
      }
      uint4 hv, lv;
      hv.x = (uint)hh[0] | ((uint)hh[1] << 16);
      hv.y = (uint)hh[2] | ((uint)hh[3] << 16);
      hv.z = (uint)hh[4] | ((uint)hh[5] << 16);
      hv.w = (uint)hh[6] | ((uint)hh[7] << 16);
      lv.x = (uint)ll[0] | ((uint)ll[1] << 16);
      lv.y = (uint)ll[2] | ((uint)ll[3] << 16);
      lv.z = (uint)ll[4] | ((uint)ll[5] << 16);
      lv.w = (uint)ll[6] | ((uint)ll[7] << 16);
      *(uint4*)((char*)sUhi + (base ^ swz)) = hv;
      *(uint4*)((char*)sUlo + (base ^ swz)) = lv;
    } else {
      uint4 z; z.x = 0; z.y = 0; z.z = 0; z.w = 0;
      *(uint4*)((char*)sUhi + (base ^ swz)) = z;
      *(uint4*)((char*)sUlo + (base ^ swz)) = z;
    }
  }
  __syncthreads();

  // ---- phase A: slot ballot ----
  bool isstart = false;
  int pre = 0;
  if (t < 128) {
    int le = t;
    isstart = (le < nE) && (le == 0 || s_srow[le] != s_srow[le - 1]);
    unsigned long long m = __ballot(isstart ? 1 : 0);
    int lane = t & 63;
    pre = __popcll(m & ((lane == 0) ? 0ull : ((~0ull) >> (64 - lane))));
    if (lane == 0) sSlotCnt[t >> 6] = __popcll(m);
  }
  __syncthreads();
  if (t < 128 && isstart) {
    int le = t;
    int slot = ((t >> 6) ? sSlotCnt[0] : 0) + pre;
    int row = s_srow[le];
    sSlotStart[slot] = le;
    int rs = rowptr[row], re = rowptr[row + 1];
    int interior = (rs >= e0 && re <= e0 + nE) ? 1 : 0;
    sSlotRowF[slot] = row | (interior << 30);
  }
  if (t == 0) sSlotStart[sSlotCnt[0] + sSlotCnt[1]] = nE;
  // published by stage-2's internal barrier

  // ---- stage 2: m^T = W2^T · u^T ----
  int l = t & 63;
  int wv = t >> 6;
  int lane16 = l & 15;
  int kq = l >> 4;

  {
    const ushort* bhp = w2h + (wv * 16 + lane16) * 64 + kq * 8;
    const ushort* blp = w2l + (wv * 16 + lane16) * 64 + kq * 8;
    bshort8 wh0 = *(const bshort8*)(bhp);
    bshort8 wh1 = *(const bshort8*)(bhp + 32);
    bshort8 wl0 = *(const bshort8*)(blp);
    bshort8 wl1 = *(const bshort8*)(blp + 32);

    f32x4 acc[8];
#pragma unroll
    for (int et = 0; et < 8; et++) {
      int edge = et * 16 + lane16;
      bshort8 uh0 = lds_frag(sUhi, edge, kq * 8);
      bshort8 uh1 = lds_frag(sUhi, edge, 32 + kq * 8);
      bshort8 ul0 = lds_frag(sUlo, edge, kq * 8);
      bshort8 ul1 = lds_frag(sUlo, edge, 32 + kq * 8);
      f32x4 a = {0.f, 0.f, 0.f, 0.f};
      a = __builtin_amdgcn_mfma_f32_16x16x32_bf16(wh0, uh0, a, 0, 0, 0);
      a = __builtin_amdgcn_mfma_f32_16x16x32_bf16(wh1, uh1, a, 0, 0, 0);
      a = __builtin_amdgcn_mfma_f32_16x16x32_bf16(wh0, ul0, a, 0, 0, 0);
      a = __builtin_amdgcn_mfma_f32_16x16x32_bf16(wh1, ul1, a, 0, 0, 0);
      a = __builtin_amdgcn_mfma_f32_16x16x32_bf16(wl0, uh0, a, 0, 0, 0);
      a = __builtin_amdgcn_mfma_f32_16x16x32_bf16(wl1, uh1, a, 0, 0, 0);
      acc[et] = a;
    }
    __syncthreads();  // all u reads done; slot tables published

    float b2r[4];
#pragma unroll
    for (int r = 0; r < 4; r++) b2r[r] = sb2v[wv * 16 + kq * 4 + r];
#pragma unroll
    for (int et = 0; et < 8; et++) {
      int edge = et * 16 + lane16;
      ushort mh[4], ml[4];
#pragma unroll
      for (int r = 0; r < 4; r++) {
        float mv = silu_f(acc[et][r] + b2r[r]);
        bf16_split(mv, mh[r], ml[r]);
      }
      int byte = (edge * 128 + (wv * 16 + kq * 4) * 2) ^ ((edge & 7) << 4);
      uint2 hv, lv;
      hv.x = (uint)mh[0] | ((uint)mh[1] << 16);
      hv.y = (uint)mh[2] | ((uint)mh[3] << 16);
      lv.x = (uint)ml[0] | ((uint)ml[1] << 16);
      lv.y = (uint)ml[2] | ((uint)ml[3] << 16);
      *(uint2*)((char*)sUhi + byte) = hv;
      *(uint2*)((char*)sUlo + byte) = lv;
    }
  }
  __syncthreads();

  // ---- stage 3 (COORD): v^T = cW1^T · m^T (m hi-only), in-thread reduce ----
  if (COORD) {
    const ushort* chp = c1h + (wv * 16 + lane16) * 64 + kq * 8;
    const ushort* clp = c1l + (wv * 16 + lane16) * 64 + kq * 8;
    bshort8 ch0 = *(const bshort8*)(chp);
    bshort8 ch1 = *(const bshort8*)(chp + 32);
    bshort8 cl0 = *(const bshort8*)(clp);
    bshort8 cl1 = *(const bshort8*)(clp + 32);
    float cb1r[4], cw2r[4];
#pragma unroll
    for (int r = 0; r < 4; r++) {
      cb1r[r] = scb1v[wv * 16 + kq * 4 + r];
      cw2r[r] = scW2v[wv * 16 + kq * 4 + r];
    }
#pragma unroll
    for (int et = 0; et < 8; et++) {
      int edge = et * 16 + lane16;
      bshort8 mh0 = lds_frag(sUhi, edge, kq * 8);
      bshort8 mh1 = lds_frag(sUhi, edge, 32 + kq * 8);
      f32x4 a = {0.f, 0.f, 0.f, 0.f};
      a = __builtin_amdgcn_mfma_f32_16x16x32_bf16(ch0, mh0, a, 0, 0, 0);
      a = __builtin_amdgcn_mfma_f32_16x16x32_bf16(ch1, mh1, a, 0, 0, 0);
      a = __builtin_amdgcn_mfma_f32_16x16x32_bf16(cl0, mh0, a, 0, 0, 0);
      a = __builtin_amdgcn_mfma_f32_16x16x32_bf16(cl1, mh1, a, 0, 0, 0);
      float pr = 0.f;
#pragma unroll
      for (int r = 0; r < 4; r++) pr += silu_f(a[r] + cb1r[r]) * cw2r[r];
      pr += __shfl_xor(pr, 16);
      pr += __shfl_xor(pr, 32);
      if (kq == 0) sPart[edge * 4 + wv] = pr;
    }
  }
  __syncthreads();
  if (COORD) {
    if (t >= 128) {
      int e = t - 128;
      sWe[e] = sPart[4 * e + 0] + sPart[4 * e + 1] + sPart[4 * e + 2] + sPart[4 * e + 3] + cb2[0];
    }
  }
  __syncthreads();

  // ---- stage 4: slot-based segmented reductions ----
  int nslots = sSlotCnt[0] + sSlotCnt[1];
  for (int task = t; task < (nslots << 5); task += 256) {
    int s = task >> 5, cp = task & 31;
    int a = sSlotStart[s], b = sSlotStart[s + 1];
    float acc0 = 0.f, acc1 = 0.f;
    for (int le = a; le < b; le++) {
      int byte = (le * 128 + cp * 4) ^ ((le & 7) << 4);
      uint hv = *(const uint*)((const char*)sUhi + byte);
      uint lv = *(const uint*)((const char*)sUlo + byte);
      acc0 += __uint_as_float(hv << 16) + __uint_as_float(lv << 16);
      acc1 += __uint_as_float(hv & 0xffff0000u) + __uint_as_float(lv & 0xffff0000u);
    }
    int rowf = sSlotRowF[s];
    int row = rowf & 0x3fffffff;
    float* ap = agg + (size_t)row * 64 + 2 * cp;
    if (rowf & (1 << 30)) {
      ap[0] = acc0; ap[1] = acc1;
    } else {
      atomicAdd(ap, acc0);
      atomicAdd(ap + 1, acc1);
    }
  }
  if (COORD) {
    for (int task = t; task < (nslots << 2); task += 256) {
      int s = task >> 2, d = task & 3;
      if (d < 3) {
        int a = sSlotStart[s], b = sSlotStart[s + 1];
        float acc = 0.f;
        for (int le = a; le < b; le++) acc += sDiff[d][le] * sWe[le];
        int row = sSlotRowF[s] & 0x3fffffff;
        atomicAdd(&posw[(size_t)row * 3 + d], acc);
      }
    }
  }
}

// ---------------- pooling + classifier ----------------
__device__ __forceinline__ int lbound(const int* __restrict__ a, int n, int v)
{
  int lo = 0, hi = n;
  while (lo < hi) {
    int mid = (lo + hi) >> 1;
    if (a[mid] < v) lo = mid + 1;
    else hi = mid;
  }
  return lo;
}

__global__ __launch_bounds__(256) void pool_cls_kernel(
    const float* __restrict__ h, const int* __restrict__ batch, int N,
    const float* __restrict__ W1, const float* __restrict__ b1,
    const float* __restrict__ W2, const float* __restrict__ b2, float* __restrict__ out)
{
  int g = blockIdx.x;
  int start = lbound(batch, N, g);
  int end = lbound(batch, N, g + 1);
  int j = threadIdx.x & 63;
  int grp = threadIdx.x >> 6;
  float s = 0.f, mx = -INFINITY;
  for (int n = start + grp; n < end; n += 4) {
    float v = h[(size_t)n * 64 + j];
    s += v;
    mx = fmaxf(mx, v);
  }
  __shared__ float ssum[4][64];
  __shared__ float smax[4][64];
  __shared__ float pooled[128];
  __shared__ float su[64];
  ssum[grp][j] = s;
  smax[grp][j] = mx;
  __syncthreads();
  if (grp == 0) {
    float S = ssum[0][j] + ssum[1][j] + ssum[2][j] + ssum[3][j];
    float M = fmaxf(fmaxf(smax[0][j], smax[1][j]), fmaxf(smax[2][j], smax[3][j]));
    float cnt = (float)(end - start);
    pooled[j] = S / fmaxf(cnt, 1.0f);
    pooled[64 + j] = M;
  }
  __syncthreads();
  if (threadIdx.x < 64) {
    float a = b1[j];
#pragma unroll
    for (int k = 0; k < 128; k++) a += pooled[k] * W1[k * 64 + j];
    su[j] = fmaxf(a, 0.f);
  }
  __syncthreads();
  if (threadIdx.x < 2) {
    float a = b2[threadIdx.x];
#pragma unroll
    for (int k = 0; k < 64; k++) a += su[k] * W2[k * 2 + threadIdx.x];
    out[g * 2 + threadIdx.x] = a;
  }
}

extern "C" void kernel_launch(void* const* d_in, const int* in_sizes, int n_in,
                              void* d_out, int out_size, void* d_ws, size_t ws_size,
                              hipStream_t stream)
{
  const float* x = (const float*)d_in[0];
  const float* pos = (const float*)d_in[1];
  const int* ei = (const int*)d_in[2];
  const float* eattr = (const float*)d_in[3];
  const int* batch = (const int*)d_in[4];
  const float* projW = (const float*)d_in[5];
  const float* projb = (const float*)d_in[6];
  const float* msgW1 = (const float*)d_in[7];
  const float* msgb1 = (const float*)d_in[8];
  const float* msgW2 = (const float*)d_in[9];
  const float* msgb2 = (const float*)d_in[10];
  const float* ndW1 = (const float*)d_in[11];
  const float* ndb1 = (const float*)d_in[12];
  const float* ndW2 = (const float*)d_in[13];
  const float* ndb2 = (const float*)d_in[14];
  const float* cdW1 = (const float*)d_in[15];
  const float* cdb1 = (const float*)d_in[16];
  const float* cdW2 = (const float*)d_in[17];
  const float* cdb2 = (const float*)d_in[18];
  const float* clsW1 = (const float*)d_in[19];
  const float* clsb1 = (const float*)d_in[20];
  const float* clsW2 = (const float*)d_in[21];
  const float* clsb2 = (const float*)d_in[22];

  int N = in_sizes[4];
  int E = in_sizes[3] / 3;
  const int* rowp = ei;
  const int* colp = ei + E;

  char* wsb = (char*)d_ws;
  size_t off = 0;
  auto alloc = [&](size_t bytes) {
    size_t o = off;
    off = (off + bytes + 255) & ~(size_t)255;
    return o;
  };
  size_t nh = (size_t)N * 64 * sizeof(float);
  size_t o_h = alloc(nh);
  size_t o_P = alloc(nh);
  size_t o_Q = alloc(nh);
  size_t o_agg = alloc(nh);
  size_t o_posA = alloc((size_t)N * 3 * sizeof(float));
  size_t o_posB = alloc((size_t)N * 3 * sizeof(float));
  size_t o_cnt = alloc((size_t)N * sizeof(int));
  size_t o_rowptr = alloc(((size_t)N + 1) * sizeof(int));
  size_t o_cursor = alloc((size_t)N * sizeof(int));
  size_t o_srow = alloc((size_t)E * sizeof(int));
  size_t o_scol = alloc((size_t)E * sizeof(int));
  size_t o_sea4 = alloc((size_t)E * 4 * sizeof(float));
  size_t o_w2h = alloc(4 * 4096 * sizeof(ushort));
  size_t o_w2l = alloc(4 * 4096 * sizeof(ushort));
  size_t o_c1h = alloc(4 * 4096 * sizeof(ushort));
  size_t o_c1l = alloc(4 * 4096 * sizeof(ushort));
  size_t o_n1h = alloc(4 * 8192 * sizeof(ushort));
  size_t o_n1l = alloc(4 * 8192 * sizeof(ushort));
  size_t o_n2h = alloc(4 * 4096 * sizeof(ushort));
  size_t o_n2l = alloc(4 * 4096 * sizeof(ushort));
  size_t o_pqh = alloc(4 * 8192 * sizeof(ushort));
  size_t o_pql = alloc(4 * 8192 * sizeof(ushort));
  size_t csr_end = off;

  float* h = (float*)(wsb + o_h);
  float* Pb = (float*)(wsb + o_P);
  float* Qb = (float*)(wsb + o_Q);
  float* agg = (float*)(wsb + o_agg);
  float* posA = (float*)(wsb + o_posA);
  float* posB = (float*)(wsb + o_posB);

  int nb_nodes = (N + 255) / 256;
  int nb_edges = (E + 255) / 256;
  int nb_tiled = (N + EB - 1) / EB;
  int G = out_size / 2;

  proj_kernel<<<nb_nodes, 256, 0, stream>>>(x, projW, projb, h, N);

  const float* pr[4] = {pos, posA, posB, posA};
  float* pw[4] = {posA, posB, posA, nullptr};

  bool use_sorted = (csr_end <= ws_size);

  if (use_sorted) {
    int* cnt = (int*)(wsb + o_cnt);
    int* rowptr = (int*)(wsb + o_rowptr);
    int* cursor = (int*)(wsb + o_cursor);
    int* srow = (int*)(wsb + o_srow);
    int* scol = (int*)(wsb + o_scol);
    float* sea4 = (float*)(wsb + o_sea4);
    ushort* w2h = (ushort*)(wsb + o_w2h);
    ushort* w2l = (ushort*)(wsb + o_w2l);
    ushort* c1h = (ushort*)(wsb + o_c1h);
    ushort* c1l = (ushort*)(wsb + o_c1l);
    ushort* n1h = (ushort*)(wsb + o_n1h);
    ushort* n1l = (ushort*)(wsb + o_n1l);
    ushort* n2h = (ushort*)(wsb + o_n2h);
    ushort* n2l = (ushort*)(wsb + o_n2l);
    ushort* pqh = (ushort*)(wsb + o_pqh);
    ushort* pql = (ushort*)(wsb + o_pql);

    hipMemsetAsync(cnt, 0, (size_t)N * sizeof(int), stream);
    hist_kernel<<<nb_edges, 256, 0, stream>>>(rowp, cnt, E);
    scan_kernel<<<1, 1024, 0, stream>>>(cnt, rowptr, cursor, N, E);
    scatter_kernel<<<nb_edges, 256, 0, stream>>>(rowp, colp, eattr, cursor, srow, scol, sea4, E);
    prep_wt_kernel<<<64, 256, 0, stream>>>(msgW2, cdW1, w2h, w2l, c1h, c1l);
    prep_nd_kernel<<<128, 256, 0, stream>>>(ndW1, ndW2, msgW1, n1h, n1l, n2h, n2l, pqh, pql);

    premul_mfma_kernel<<<nb_tiled, 256, 0, stream>>>(h, pqh, pql, Pb, Qb, N);

    int nb_fused = (E + EB - 1) / EB;
    for (int i = 0; i < 4; i++) {
      hipMemsetAsync(agg, 0, nh, stream);
      if (i < 3) {
        hipMemcpyAsync(pw[i], pr[i], (size_t)N * 3 * sizeof(float), hipMemcpyDeviceToDevice,
                       stream);
        edge_fused_kernel<1><<<nb_fused, 256, 0, stream>>>(
            srow, scol, rowptr, pr[i], pw[i], sea4, Pb, Qb,
            msgW1 + (size_t)i * 132 * 64 + 128 * 64, msgb1 + i * 64,
            w2h + (size_t)i * 4096, w2l + (size_t)i * 4096, msgb2 + i * 64,
            c1h + (size_t)i * 4096, c1l + (size_t)i * 4096,
            cdb1 + i * 64, cdW2 + i * 64, cdb2 + i, agg, E);
        node_mfma_kernel<1><<<nb_tiled, 256, 0, stream>>>(
            h, agg, n1h + (size_t)i * 8192, n1l + (size_t)i * 8192, ndb1 + i * 64,
            n2h + (size_t)i * 4096, n2l + (size_t)i * 4096, ndb2 + i * 64,
            pqh + (size_t)(i + 1) * 8192, pql + (size_t)(i + 1) * 8192, Pb, Qb, N);
      } else {
        edge_fused_kernel<0><<<nb_fused, 256, 0, stream>>>(
            srow, scol, rowptr, pr[i], nullptr, sea4, Pb, Qb,
            msgW1 + (size_t)i * 132 * 64 + 128 * 64, msgb1 + i * 64,
            w2h + (size_t)i * 4096, w2l + (size_t)i * 4096, msgb2 + i * 64,
            nullptr, nullptr, nullptr, nullptr, nullptr, agg, E);
        node_mfma_kernel<0><<<nb_tiled, 256, 0, stream>>>(
            h, agg, n1h + (size_t)i * 8192, n1l + (size_t)i * 8192, ndb1 + i * 64,
            n2h + (size_t)i * 4096, n2l + (size_t)i * 4096, ndb2 + i * 64,
            nullptr, nullptr, nullptr, nullptr, N);
      }
    }
  }

  pool_cls_kernel<<<G, 256, 0, stream>>>(h, batch, N, clsW1, clsb1, clsW2, clsb2, (float*)d_out);
}